// Round 8
// baseline (513.954 us; speedup 1.0000x reference)
//
#include <hip/hip_runtime.h>

#define NN     1024
#define IN_D   256
#define OUT_D  256
#define BN     4               // n-rows per block; grid = 256 = 1 block/CU
#define NI2    (IN_D / 2)      // 128 ii-pairs
#define NG     8               // K-groups (tid>>7), 32 i's each
#define JPG    (NI2 / NG)      // 16 ii-pairs per group
#define PH     4               // phases per group
#define JP     (JPG / PH)      // 4 j per phase (8 batched dwordx4 loads/phase)
#define OSLOTS (OUT_D / 2)     // 128; thread owns o = oslot and oslot+128

typedef float v2f __attribute__((ext_vector_type(2)));
typedef float v4f __attribute__((ext_vector_type(4)));

// ws: float4 wlr2[ii2*OUT+o] = {wl(2ii2,o), wr(2ii2,o), wl(2ii2+1,o), wr(2ii2+1,o)}
#define WLR_BYTES (sizeof(float4) * NI2 * OUT_D)   // 512 KB

__global__ __launch_bounds__(256) void fz_prep(
    const float* __restrict__ wb, const float* __restrict__ wa,
    const float* __restrict__ wc, float4* __restrict__ wlr2) {
    int t = blockIdx.x * 256 + threadIdx.x;        // 0 .. NI2*OUT-1
    int ii2 = t >> 8;
    int o   = t & (OUT_D - 1);
    int i0  = (2 * ii2) * OUT_D + o;
    int i1  = i0 + OUT_D;
    float4 w;
    w.x = wb[i0] - fmaxf(wa[i0], 0.0f);
    w.y = wb[i0] + fmaxf(wc[i0], 0.0f);
    w.z = wb[i1] - fmaxf(wa[i1], 0.0f);
    w.w = wb[i1] + fmaxf(wc[i1], 0.0f);
    wlr2[t] = w;
}

__device__ __forceinline__ void fz_tri(float a, float b, float wl, float wr,
                                       float& aL, float& aR) {
    // invariants: b >= a (hr >= hl), wr > 0
    //   min(p1..p4) = min3(a*wl, b*wl, a*wr); max(p1..p4) = max3(a*wl, b*wl, b*wr)
    float x  = a * wl;
    float y  = b * wl;
    float zl = a * wr;
    float zr = b * wr;
    aL += fminf(fminf(x, y), zl);                  // -> v_min3_f32 + add
    aR += fmaxf(fmaxf(x, y), zr);                  // -> v_max3_f32 + add
}

template <bool PREP>
__global__ __launch_bounds__(1024, 4) void fz_fused(
    const float* __restrict__ hl, const float* __restrict__ hr,
    const float* __restrict__ wb, const float* __restrict__ wa,
    const float* __restrict__ wc, const float4* __restrict__ wlr2,
    const float* __restrict__ bb, const float* __restrict__ ba,
    const float* __restrict__ bc, float* __restrict__ out) {
    __shared__ __align__(16) v2f ab[BN][IN_D];            // 8 KB {hl,hr}
    __shared__ __align__(16) v2f pl[NG][BN][2][OSLOTS];   // 64 KB partials

    const int tid   = threadIdx.x;
    const int oslot = tid & (OSLOTS - 1);          // o0 = oslot, o1 = oslot+128
    const int g     = tid >> 7;                    // K-group 0..7
    const int n0    = blockIdx.x * BN;

    // stage BN rows of {hl,hr}: one (row, ii) per thread, coalesced
    {
        int row = tid >> 8;
        int ii  = tid & (IN_D - 1);
        v2f v; v.x = hl[(n0 + row) * IN_D + ii];
        v.y = hr[(n0 + row) * IN_D + ii];
        ab[row][ii] = v;
    }
    __syncthreads();

    float accL[BN][2], accR[BN][2];
#pragma unroll
    for (int t = 0; t < BN; ++t) {
        accL[t][0] = 0.0f; accL[t][1] = 0.0f;
        accR[t][0] = 0.0f; accR[t][1] = 0.0f;
    }

    const int j0 = g * JPG;
    const float4* wp0 = wlr2 + (size_t)j0 * OUT_D + oslot;   // o0 stream
    const float4* wp1 = wp0 + OSLOTS;                        // o1 stream

    // depth-1 prefetch of the h LDS reads
    v4f a4c[BN], a4n[BN];
#pragma unroll
    for (int t = 0; t < BN; ++t)
        a4c[t] = *reinterpret_cast<const v4f*>(&ab[t][j0 * 2]);

    // W batch registers for one phase: 8 float4 = 32 VGPR
    float4 wA[JP], wB[JP];

#pragma unroll
    for (int p = 0; p < PH; ++p) {
        // ---- batch-issue all W loads for this phase (progressive vmcnt) ----
#pragma unroll
        for (int jj = 0; jj < JP; ++jj) {
            const int j = p * JP + jj;
            if (PREP) {
                wA[jj] = wp0[(size_t)j * OUT_D];
                wB[jj] = wp1[(size_t)j * OUT_D];
            } else {
                int base = (j0 + j) * 2 * OUT_D + oslot;
                float b00 = wb[base], a00 = wa[base], c00 = wc[base];
                float b10 = wb[base + OUT_D], a10 = wa[base + OUT_D], c10 = wc[base + OUT_D];
                wA[jj].x = b00 - fmaxf(a00, 0.0f); wA[jj].y = b00 + fmaxf(c00, 0.0f);
                wA[jj].z = b10 - fmaxf(a10, 0.0f); wA[jj].w = b10 + fmaxf(c10, 0.0f);
                int b1 = base + OSLOTS;
                float b01 = wb[b1], a01 = wa[b1], c01 = wc[b1];
                float b11 = wb[b1 + OUT_D], a11 = wa[b1 + OUT_D], c11 = wc[b1 + OUT_D];
                wB[jj].x = b01 - fmaxf(a01, 0.0f); wB[jj].y = b01 + fmaxf(c01, 0.0f);
                wB[jj].z = b11 - fmaxf(a11, 0.0f); wB[jj].w = b11 + fmaxf(c11, 0.0f);
            }
        }
        // ---- compute the phase's 4 j's ----
#pragma unroll
        for (int jj = 0; jj < JP; ++jj) {
            const int j = p * JP + jj;
            if (j + 1 < JPG) {                     // static under full unroll
                const int iin = (j0 + j + 1) * 2;
#pragma unroll
                for (int t = 0; t < BN; ++t)
                    a4n[t] = *reinterpret_cast<const v4f*>(&ab[t][iin]);
            }
            const float4 w0 = wA[jj], w1 = wB[jj];
#pragma unroll
            for (int t = 0; t < BN; ++t) {
                v4f a4 = a4c[t];
                fz_tri(a4.x, a4.y, w0.x, w0.y, accL[t][0], accR[t][0]);  // o0, i_a
                fz_tri(a4.z, a4.w, w0.z, w0.w, accL[t][0], accR[t][0]);  // o0, i_b
                fz_tri(a4.x, a4.y, w1.x, w1.y, accL[t][1], accR[t][1]);  // o1, i_a
                fz_tri(a4.z, a4.w, w1.z, w1.w, accL[t][1], accR[t][1]);  // o1, i_b
            }
#pragma unroll
            for (int t = 0; t < BN; ++t) a4c[t] = a4n[t];
        }
    }

    // partials (8B stride: 2-way aliasing = free)
#pragma unroll
    for (int t = 0; t < BN; ++t) {
        v2f p0; p0.x = accL[t][0]; p0.y = accR[t][0];
        v2f p1; p1.x = accL[t][1]; p1.y = accR[t][1];
        pl[g][t][0][oslot] = p0;
        pl[g][t][1][oslot] = p1;
    }
    __syncthreads();

    // epilogue: all 8 groups — g = half*4 + row
    {
        const int row  = g & 3;
        const int half = g >> 2;
        const int o    = oslot + half * OSLOTS;
        v2f s = (v2f)(0.0f);
#pragma unroll
        for (int gg = 0; gg < NG; ++gg)
            s += pl[gg][row][half][oslot];
        float bl = bb[o] - fmaxf(ba[o], 0.0f);
        float br = bb[o] + fmaxf(bc[o], 0.0f);
        size_t rl = (size_t)(n0 + row) * OUT_D + o;
        out[rl]                 = s.x + bl;
        out[(size_t)NN * OUT_D + rl] = s.y + br;
    }
}

extern "C" void kernel_launch(void* const* d_in, const int* in_sizes, int n_in,
                              void* d_out, int out_size, void* d_ws, size_t ws_size,
                              hipStream_t stream) {
    const float* hl = (const float*)d_in[0];
    const float* hr = (const float*)d_in[1];
    const float* wb = (const float*)d_in[2];
    const float* wa = (const float*)d_in[3];
    const float* wc = (const float*)d_in[4];
    const float* bb = (const float*)d_in[5];
    const float* ba = (const float*)d_in[6];
    const float* bc = (const float*)d_in[7];
    float* out = (float*)d_out;

    dim3 grid(NN / BN);

    if (ws_size >= WLR_BYTES) {
        float4* wlr2 = (float4*)d_ws;
        fz_prep<<<(NI2 * OUT_D) / 256, 256, 0, stream>>>(wb, wa, wc, wlr2);
        fz_fused<true><<<grid, 1024, 0, stream>>>(hl, hr, wb, wa, wc, wlr2,
                                                  bb, ba, bc, out);
    } else {
        fz_fused<false><<<grid, 1024, 0, stream>>>(hl, hr, wb, wa, wc, nullptr,
                                                   bb, ba, bc, out);
    }
}